// Round 6
// baseline (172.127 us; speedup 1.0000x reference)
//
#include <hip/hip_runtime.h>
#include <math.h>

#define INV2PI 0.15915494309189535f  // 1/(2*pi)

// Measured on gfx950 (r4/r5 fit): v_sin_f32/v_cos_f32 throughput ~32-34
// cyc/wave64 (~2 lanes/cyc/SIMD), NOT quarter-rate.  dur was invariant at
// ~59us across occupancy/LDS/VGPR changes = trans-pipe saturated
// (2048 wave-elems/SIMD x 2 trans x 34cyc = 58us).  VALUBusy 48% counted
// only regular VALU -> VALU pipe was ~2/3 idle.  Fix: hybrid split --
// 7/16 of elements use hw sin/cos (trans pipe), 9/16 use a 7-term Taylor
// z-poly over the full period (VALU only, max err ~5e-4, harmless vs
// threshold 27.8).  Both pipes co-saturate at ~24us.

// sin(2*pi*a) / cos(2*pi*a) for a = t0 - 0.5 (mod 1), v = fract(t0)-0.5:
__device__ __forceinline__ float2 sincos_poly(float t0) {
    const float v = __builtin_amdgcn_fractf(t0) - 0.5f;
    const float z = v * v;
    // sin(2*pi*v) = v*(S0 + S1 z + ... + S6 z^6), Taylor, |err| <= 2.3e-5
    float s = fmaf(z, 3.8199526f, -15.094643f);
    s = fmaf(z, s, 42.058693f);
    s = fmaf(z, s, -76.705860f);
    s = fmaf(z, s, 81.605249f);
    s = fmaf(z, s, -41.341702f);
    s = fmaf(z, s, 6.2831853f);
    s *= v;
    // cos(2*pi*v) = C0 + C1 z + ... + C6 z^6, |err| <= 1.1e-4
    float c = fmaf(z, 7.9035364f, -26.426257f);
    c = fmaf(z, c, 60.244641f);
    c = fmaf(z, c, -85.456817f);
    c = fmaf(z, c, 64.939394f);
    c = fmaf(z, c, -19.739209f);
    c = fmaf(z, c, 1.0f);
    return make_float2(s, c);
}

// ---------------------------------------------------------------------------
// Kernel 1 (v6): sums.  lanes = d (each lane owns 2 d's per chunk).
// Block = 512 thr = 8 waves = 2 neurons x 4 b-quarters.  Grid = 1024.
// Chunk = 128 d's (x_s = 32 KB).  iw' = INV2PI/(1+|W|), bp' = Bp*INV2PI+0.5
// in VGPRs (the +0.5 pre-shift makes fract(t0) = a+0.5 mod 1, so the hw
// path uses the negation identity sin(2pi a) = -sin(2pi fract(t0)) and the
// poly path uses v = fract(t0)-0.5 directly).
// Hot loop per j (2 elems): 1 ds_read_b64 + either {2 fma, 2 fract, 4 trans,
// 4 sub} (j even, j<14: 7/16 of work) or {2 fma, 2 fract, 2 sub, 26 poly
// VALU} (9/16 of work).
// Epilogue: XOR-swizzled per-wave LDS transpose + shfl_xor, then rotation
// by t (exact identity):  sum cos(2pi a + t) = cos(t)*A_c - sin(t)*A_s.
// ---------------------------------------------------------------------------
__global__ __launch_bounds__(512) void k_sums(
    const float* __restrict__ x, const float* __restrict__ t,
    const float* __restrict__ W, const float* __restrict__ Bp,
    float2* __restrict__ S2)
{
    __shared__ float x_s[64 * 128];   // 32 KB

    const int tid  = threadIdx.x;
    const int lane = tid & 63;
    const int wid  = __builtin_amdgcn_readfirstlane(tid >> 6);  // 0..7
    const int nl   = wid & 1;
    const int bq   = wid >> 1;
    const int n    = blockIdx.x * 2 + nl;

    float accC[16], accS[16];
    #pragma unroll
    for (int j = 0; j < 16; ++j) { accC[j] = 0.f; accS[j] = 0.f; }

    const float4* x4 = reinterpret_cast<const float4*>(x);

    for (int c = 0; c < 8; ++c) {
        __syncthreads();

        // ---- stage x chunk: 64 b x 32 float4 = 2048 float4s ----
        #pragma unroll
        for (int i = 0; i < 4; ++i) {
            int f4 = i * 512 + tid;
            int b  = f4 >> 5;
            int dq = f4 & 31;
            float4 v = x4[b * 256 + c * 32 + dq];
            *reinterpret_cast<float4*>(&x_s[f4 << 2]) = v;
        }

        // ---- iw'/bp' (+0.5 phase pre-shift folded into bp') ----
        float2 w2 = *reinterpret_cast<const float2*>(W  + (size_t)n * 1024 + c * 128 + 2 * lane);
        float2 b2 = *reinterpret_cast<const float2*>(Bp + (size_t)n * 1024 + c * 128 + 2 * lane);
        const float iwx = INV2PI / (1.f + fabsf(w2.x));
        const float iwy = INV2PI / (1.f + fabsf(w2.y));
        const float bpx = fmaf(b2.x, INV2PI, 0.5f);
        const float bpy = fmaf(b2.y, INV2PI, 0.5f);

        __syncthreads();

        // ---- hot loop: 16 b's, static trans/poly interleave ----
        #pragma unroll
        for (int j = 0; j < 16; ++j) {
            const float2 xv = *reinterpret_cast<const float2*>(
                &x_s[(bq * 16 + j) * 128 + 2 * lane]);
            const float t0x = fmaf(xv.x, iwx, bpx);
            const float t0y = fmaf(xv.y, iwy, bpy);
            if (((j & 1) == 0) && (j < 14)) {
                // hw trans path: sin(2pi a) = -sin(2pi fract(a+0.5))
                const float rx = __builtin_amdgcn_fractf(t0x);
                const float ry = __builtin_amdgcn_fractf(t0y);
                accC[j] -= __builtin_amdgcn_cosf(rx);
                accS[j] -= __builtin_amdgcn_sinf(rx);
                accC[j] -= __builtin_amdgcn_cosf(ry);
                accS[j] -= __builtin_amdgcn_sinf(ry);
            } else {
                // VALU poly path (true sin/cos, add directly)
                const float2 scx = sincos_poly(t0x);
                const float2 scy = sincos_poly(t0y);
                accS[j] += scx.x;
                accC[j] += scx.y;
                accS[j] += scy.x;
                accC[j] += scy.y;
            }
        }
    }

    // ---- epilogue: reduce acc[16] across 64 lanes (two passes) ------------
    __syncthreads();
    float* sl = x_s + (wid << 10);         // private 1024-float slice
    const int g  = lane >> 4;
    const int bb = lane & 15;

    #pragma unroll
    for (int j = 0; j < 16; ++j) sl[j * 64 + (lane ^ j)] = accC[j];
    float sC = 0.f;
    #pragma unroll
    for (int k = 0; k < 16; ++k) sC += sl[bb * 64 + ((g * 16 + k) ^ bb)];

    #pragma unroll
    for (int j = 0; j < 16; ++j) sl[j * 64 + (lane ^ j)] = accS[j];
    float sS = 0.f;
    #pragma unroll
    for (int k = 0; k < 16; ++k) sS += sl[bb * 64 + ((g * 16 + k) ^ bb)];

    sC += __shfl_xor(sC, 16);
    sS += __shfl_xor(sS, 16);
    sC += __shfl_xor(sC, 32);
    sS += __shfl_xor(sS, 32);

    if (lane < 16) {
        const int b  = bq * 16 + lane;
        const float tv = t[b];
        const float ct = cosf(tv), st = sinf(tv);
        S2[n * 64 + b] = make_float2(ct * sC - st * sS,
                                     st * sC + ct * sS);
    }
}

// ---------------------------------------------------------------------------
// Kernel 2: split-K GEMM (unchanged from r5).
// out^T[d][b] = sum_n Pr[d][n]*c[n][b] + Pi[d][n]*s[n][b]
// grid = (128 d-tiles of 8, 8 k-chunks of 256).  Wave: 2 d-rows, lanes = b.
// ---------------------------------------------------------------------------
__global__ __launch_bounds__(256) void k_gemm(
    const float2* __restrict__ S2, const float* __restrict__ Pr,
    const float* __restrict__ Pi, float* __restrict__ partial)
{
    const int lane = threadIdx.x & 63;
    const int wid  = __builtin_amdgcn_readfirstlane(threadIdx.x >> 6);
    const int d0   = blockIdx.x * 8 + wid * 2;
    const int k0   = blockIdx.y * 256;

    const float* pr = Pr + (size_t)d0 * 2048 + k0;
    const float* pi = Pi + (size_t)d0 * 2048 + k0;

    float a0 = 0.f, a1 = 0.f;

    for (int kk = 0; kk < 256; kk += 8) {
        float2 cs[8];
        #pragma unroll
        for (int i = 0; i < 8; ++i)
            cs[i] = S2[(size_t)(k0 + kk + i) * 64 + lane];
        #pragma unroll
        for (int i = 0; i < 8; ++i) {
            a0 += pr[kk + i]        * cs[i].x + pi[kk + i]        * cs[i].y;
            a1 += pr[2048 + kk + i] * cs[i].x + pi[2048 + kk + i] * cs[i].y;
        }
    }

    float* p = partial + ((size_t)blockIdx.y * 1024 + d0) * 64 + lane;
    p[0]  = a0;
    p[64] = a1;
}

// ---------------------------------------------------------------------------
// Kernel 3: reduce 8 split-K partials + SiLU (unchanged from r5).
// ---------------------------------------------------------------------------
__global__ __launch_bounds__(256, 4) void k_reduce_silu(
    const float* __restrict__ partial, float* __restrict__ out)
{
    const int lane = threadIdx.x & 63;
    const int gw   = blockIdx.x * 4 + (threadIdx.x >> 6);
    const int b    = gw >> 4;
    const int d    = ((gw & 15) << 6) + lane;

    float s = 0.f;
    #pragma unroll
    for (int ss = 0; ss < 8; ++ss)
        s += partial[((size_t)ss * 1024 + d) * 64 + b];

    float sig = 1.0f / (1.0f + __expf(-s));
    out[(size_t)b * 1024 + d] = s * sig;
}

// ---------------------------------------------------------------------------
extern "C" void kernel_launch(void* const* d_in, const int* in_sizes, int n_in,
                              void* d_out, int out_size, void* d_ws, size_t ws_size,
                              hipStream_t stream)
{
    const float* x  = (const float*)d_in[0];   // (64,1024)
    const float* t  = (const float*)d_in[1];   // (64,)
    const float* W  = (const float*)d_in[2];   // (2048,1024)
    const float* Bp = (const float*)d_in[3];   // (2048,1024)
    const float* Pr = (const float*)d_in[4];   // (1024,2048)
    const float* Pi = (const float*)d_in[5];   // (1024,2048)
    // d_in[6], d_in[7]: sin/cos LUT — superseded by hw sin/cos + VALU poly

    float*  out     = (float*)d_out;                       // (64,1024) f32
    float2* S2      = (float2*)d_ws;                       // 1 MB
    float*  partial = (float*)((char*)d_ws + (1 << 20));   // 2 MB

    k_sums<<<1024, 512, 0, stream>>>(x, t, W, Bp, S2);
    k_gemm<<<dim3(128, 8), 256, 0, stream>>>(S2, Pr, Pi, partial);
    k_reduce_silu<<<256, 256, 0, stream>>>(partial, out);
}

// Round 8
// 163.141 us; speedup vs baseline: 1.0551x; 1.0551x over previous
//
#include <hip/hip_runtime.h>
#include <math.h>

#define INV2PI 0.15915494309189535f  // 1/(2*pi)

// Model status after r6 differential experiment:
//  - v_sin/v_cos ~8.5 cyc/wave64 issue (quarter rate).  Trans-pipe time for
//    the whole op is only ~14.5 us -- NOT the bound.
//  - VALUBusy excludes trans; poly path cost showed up 1:1 in VALUBusy and
//    regressed dur => drop poly, all elements on hw trans.
//  - r2/r4/r5 all ~52-59 us with no pipe >50% busy and occupancy pinned at
//    ~41% => latency-bound: compiler chose VGPR=36 (8-wave target), leaving
//    serial ds_read->fma->fract->sin->add chains; ~3.3 real waves/SIMD can't
//    hide trans latency.
//  - total - k_sums = 104-112 us across 4 different k_gemm/k_reduce configs
//    => residual is harness restore/replay overhead, not kernel time.
// v7: force ILP.  Per chunk: phase A computes 32 fract values into a live
// register array; sched_barrier(0); phase B issues 64 independent trans ops.
// VGPR target ~90-100 (acc 32 + r 32 + misc) -> ~4-5 waves/SIMD cap, with
// 64-deep per-wave trans ILP doing the hiding.

// ---------------------------------------------------------------------------
// Kernel 1 (v7): sums.  lanes = d (2 d's per lane per chunk).
// Block = 512 thr = 8 waves = 2 neurons x 4 b-quarters.  Grid = 1024.
// Chunk = 128 d's (x_s = 32 KB).  iw' = INV2PI/(1+|W|), bp' = Bp*INV2PI in
// VGPRs (coalesced float2 global loads; zero LDS traffic for W/Bp).
// Epilogue: XOR-swizzled per-wave LDS transpose + shfl_xor, then rotation
// by t (exact identity):  sum cos(2pi a + t) = cos(t)*A_c - sin(t)*A_s.
// ---------------------------------------------------------------------------
__global__ __launch_bounds__(512) void k_sums(
    const float* __restrict__ x, const float* __restrict__ t,
    const float* __restrict__ W, const float* __restrict__ Bp,
    float2* __restrict__ S2)
{
    __shared__ float x_s[64 * 128];   // 32 KB

    const int tid  = threadIdx.x;
    const int lane = tid & 63;
    const int wid  = __builtin_amdgcn_readfirstlane(tid >> 6);  // 0..7
    const int nl   = wid & 1;
    const int bq   = wid >> 1;
    const int n    = blockIdx.x * 2 + nl;

    float accC[16], accS[16];
    #pragma unroll
    for (int j = 0; j < 16; ++j) { accC[j] = 0.f; accS[j] = 0.f; }

    const float4* x4 = reinterpret_cast<const float4*>(x);

    for (int c = 0; c < 8; ++c) {
        __syncthreads();

        // ---- stage x chunk: 64 b x 32 float4 = 2048 float4s ----
        #pragma unroll
        for (int i = 0; i < 4; ++i) {
            int f4 = i * 512 + tid;
            int b  = f4 >> 5;
            int dq = f4 & 31;
            float4 v = x4[b * 256 + c * 32 + dq];
            *reinterpret_cast<float4*>(&x_s[f4 << 2]) = v;
        }

        // ---- this chunk's iw'/bp': 4 VGPRs, global coalesced ----
        float2 w2 = *reinterpret_cast<const float2*>(W  + (size_t)n * 1024 + c * 128 + 2 * lane);
        float2 b2 = *reinterpret_cast<const float2*>(Bp + (size_t)n * 1024 + c * 128 + 2 * lane);
        const float iwx = INV2PI / (1.f + fabsf(w2.x));
        const float iwy = INV2PI / (1.f + fabsf(w2.y));
        const float bpx = b2.x * INV2PI;
        const float bpy = b2.y * INV2PI;

        __syncthreads();

        // ---- phase A: 32 fract results into live registers ----
        float r[32];
        #pragma unroll
        for (int j = 0; j < 16; ++j) {
            const float2 xv = *reinterpret_cast<const float2*>(
                &x_s[(bq * 16 + j) * 128 + 2 * lane]);
            r[2 * j]     = __builtin_amdgcn_fractf(fmaf(xv.x, iwx, bpx));
            r[2 * j + 1] = __builtin_amdgcn_fractf(fmaf(xv.y, iwy, bpy));
        }

        __builtin_amdgcn_sched_barrier(0);   // keep phases separate: r[] stays
                                             // live -> 64-deep trans ILP below

        // ---- phase B: 64 independent trans ops, short acc chains ----
        #pragma unroll
        for (int j = 0; j < 16; ++j) {
            const float c0 = __builtin_amdgcn_cosf(r[2 * j]);
            const float c1 = __builtin_amdgcn_cosf(r[2 * j + 1]);
            const float s0 = __builtin_amdgcn_sinf(r[2 * j]);
            const float s1 = __builtin_amdgcn_sinf(r[2 * j + 1]);
            accC[j] += c0 + c1;
            accS[j] += s0 + s1;
        }
    }

    // ---- epilogue: reduce acc[16] across 64 lanes (two passes) ------------
    __syncthreads();
    float* sl = x_s + (wid << 10);         // private 1024-float slice
    const int g  = lane >> 4;
    const int bb = lane & 15;

    #pragma unroll
    for (int j = 0; j < 16; ++j) sl[j * 64 + (lane ^ j)] = accC[j];
    float sC = 0.f;
    #pragma unroll
    for (int k = 0; k < 16; ++k) sC += sl[bb * 64 + ((g * 16 + k) ^ bb)];

    #pragma unroll
    for (int j = 0; j < 16; ++j) sl[j * 64 + (lane ^ j)] = accS[j];
    float sS = 0.f;
    #pragma unroll
    for (int k = 0; k < 16; ++k) sS += sl[bb * 64 + ((g * 16 + k) ^ bb)];

    sC += __shfl_xor(sC, 16);
    sS += __shfl_xor(sS, 16);
    sC += __shfl_xor(sC, 32);
    sS += __shfl_xor(sS, 32);

    if (lane < 16) {
        const int b  = bq * 16 + lane;
        const float tv = t[b];
        const float ct = cosf(tv), st = sinf(tv);
        S2[n * 64 + b] = make_float2(ct * sC - st * sS,
                                     st * sC + ct * sS);
    }
}

// ---------------------------------------------------------------------------
// Kernel 2: split-K GEMM (unchanged).
// out^T[d][b] = sum_n Pr[d][n]*c[n][b] + Pi[d][n]*s[n][b]
// grid = (128 d-tiles of 8, 8 k-chunks of 256).  Wave: 2 d-rows, lanes = b.
// ---------------------------------------------------------------------------
__global__ __launch_bounds__(256) void k_gemm(
    const float2* __restrict__ S2, const float* __restrict__ Pr,
    const float* __restrict__ Pi, float* __restrict__ partial)
{
    const int lane = threadIdx.x & 63;
    const int wid  = __builtin_amdgcn_readfirstlane(threadIdx.x >> 6);
    const int d0   = blockIdx.x * 8 + wid * 2;
    const int k0   = blockIdx.y * 256;

    const float* pr = Pr + (size_t)d0 * 2048 + k0;
    const float* pi = Pi + (size_t)d0 * 2048 + k0;

    float a0 = 0.f, a1 = 0.f;

    for (int kk = 0; kk < 256; kk += 8) {
        float2 cs[8];
        #pragma unroll
        for (int i = 0; i < 8; ++i)
            cs[i] = S2[(size_t)(k0 + kk + i) * 64 + lane];
        #pragma unroll
        for (int i = 0; i < 8; ++i) {
            a0 += pr[kk + i]        * cs[i].x + pi[kk + i]        * cs[i].y;
            a1 += pr[2048 + kk + i] * cs[i].x + pi[2048 + kk + i] * cs[i].y;
        }
    }

    float* p = partial + ((size_t)blockIdx.y * 1024 + d0) * 64 + lane;
    p[0]  = a0;
    p[64] = a1;
}

// ---------------------------------------------------------------------------
// Kernel 3: reduce 8 split-K partials + SiLU (unchanged).
// ---------------------------------------------------------------------------
__global__ __launch_bounds__(256, 4) void k_reduce_silu(
    const float* __restrict__ partial, float* __restrict__ out)
{
    const int lane = threadIdx.x & 63;
    const int gw   = blockIdx.x * 4 + (threadIdx.x >> 6);
    const int b    = gw >> 4;
    const int d    = ((gw & 15) << 6) + lane;

    float s = 0.f;
    #pragma unroll
    for (int ss = 0; ss < 8; ++ss)
        s += partial[((size_t)ss * 1024 + d) * 64 + b];

    float sig = 1.0f / (1.0f + __expf(-s));
    out[(size_t)b * 1024 + d] = s * sig;
}

// ---------------------------------------------------------------------------
extern "C" void kernel_launch(void* const* d_in, const int* in_sizes, int n_in,
                              void* d_out, int out_size, void* d_ws, size_t ws_size,
                              hipStream_t stream)
{
    const float* x  = (const float*)d_in[0];   // (64,1024)
    const float* t  = (const float*)d_in[1];   // (64,)
    const float* W  = (const float*)d_in[2];   // (2048,1024)
    const float* Bp = (const float*)d_in[3];   // (2048,1024)
    const float* Pr = (const float*)d_in[4];   // (1024,2048)
    const float* Pi = (const float*)d_in[5];   // (1024,2048)
    // d_in[6], d_in[7]: sin/cos LUT — superseded by hw sin/cos

    float*  out     = (float*)d_out;                       // (64,1024) f32
    float2* S2      = (float2*)d_ws;                       // 1 MB
    float*  partial = (float*)((char*)d_ws + (1 << 20));   // 2 MB

    k_sums<<<1024, 512, 0, stream>>>(x, t, W, Bp, S2);
    k_gemm<<<dim3(128, 8), 256, 0, stream>>>(S2, Pr, Pi, partial);
    k_reduce_silu<<<256, 256, 0, stream>>>(partial, out);
}

// Round 9
// 154.649 us; speedup vs baseline: 1.1130x; 1.0549x over previous
//
#include <hip/hip_runtime.h>
#include <math.h>

#define INV2PI 0.15915494309189535f  // 1/(2*pi)

// Model (r6/r8 differentials):
//  - v_sin/v_cos ~quarter-rate issue; whole-op trans time ~14 us, NOT the bound.
//  - v7 (in-chunk ILP) 59->50.5 us; remaining gap = barrier/stage stalls:
//    2 __syncthreads x 8 chunks with 8 lock-step waves.
//  - x is 256 KB = L2-resident; LDS staging buys nothing over L2 (FETCH
//    already at compulsory ~9.2 MB) but costs 16 barriers.
// v8: ZERO barriers.  Waves fully independent; x read directly from global
// (coalesced float2/lane, L2-hit).  2 neurons per wave -> each x float2
// feeds 4 elements (8 trans), halving L2 x-traffic (~268 MB ~ 7.8 us at
// 34.5 TB/s).  LDS only for the per-wave epilogue reduce slice.

// ---------------------------------------------------------------------------
// Kernel 1 (v8): sums.  lanes = d (2 d's per lane per chunk).
// Wave = (neuron pair, b-quarter).  4096 waves = 1024 blocks x 256 thr.
// Per chunk (128 d's): 4 float2 loads (W,Bp for n0,n1) + 2x8 x-loads
// (phase A, 8-deep) + 2x{32 fma/fract + 64 trans + 64 adds} (phase B).
// Epilogue: per-wave XOR-swizzled LDS transpose reduce (4 passes) +
// shfl_xor(16,32), then rotation by t (exact identity):
//   sum cos(2pi a + t) = cos(t)*A_c - sin(t)*A_s
// ---------------------------------------------------------------------------
__global__ __launch_bounds__(256) void k_sums(
    const float* __restrict__ x, const float* __restrict__ t,
    const float* __restrict__ W, const float* __restrict__ Bp,
    float2* __restrict__ S2)
{
    __shared__ float sl_all[4][1024];   // 16 KB, epilogue only

    const int tid  = threadIdx.x;
    const int lane = tid & 63;
    const int w    = tid >> 6;                 // wave in block 0..3
    const int gw   = blockIdx.x * 4 + w;       // 0..4095
    const int n2   = gw >> 2;                  // neuron pair 0..1023
    const int bq   = gw & 3;                   // b-quarter
    const int n0   = n2 * 2, n1 = n0 + 1;

    float aC0[16], aS0[16], aC1[16], aS1[16];
    #pragma unroll
    for (int j = 0; j < 16; ++j) { aC0[j]=0.f; aS0[j]=0.f; aC1[j]=0.f; aS1[j]=0.f; }

    const float* xb = x + (size_t)(bq * 16) * 1024 + 2 * lane;

    for (int c = 0; c < 8; ++c) {
        const int dof = c * 128;

        // per-chunk wavelength/phase params for both neurons (L2-resident)
        const float2 w0 = *reinterpret_cast<const float2*>(W  + (size_t)n0 * 1024 + dof + 2 * lane);
        const float2 w1 = *reinterpret_cast<const float2*>(W  + (size_t)n1 * 1024 + dof + 2 * lane);
        const float2 p0 = *reinterpret_cast<const float2*>(Bp + (size_t)n0 * 1024 + dof + 2 * lane);
        const float2 p1 = *reinterpret_cast<const float2*>(Bp + (size_t)n1 * 1024 + dof + 2 * lane);
        const float iw0x = INV2PI / (1.f + fabsf(w0.x));
        const float iw0y = INV2PI / (1.f + fabsf(w0.y));
        const float iw1x = INV2PI / (1.f + fabsf(w1.x));
        const float iw1y = INV2PI / (1.f + fabsf(w1.y));
        const float bp0x = p0.x * INV2PI;
        const float bp0y = p0.y * INV2PI;
        const float bp1x = p1.x * INV2PI;
        const float bp1y = p1.y * INV2PI;

        // two half-batches of 8 b's: 8 independent L2 loads, then compute
        #pragma unroll
        for (int h = 0; h < 2; ++h) {
            float2 xv[8];
            #pragma unroll
            for (int j = 0; j < 8; ++j)
                xv[j] = *reinterpret_cast<const float2*>(xb + (size_t)(h * 8 + j) * 1024 + dof);

            #pragma unroll
            for (int j = 0; j < 8; ++j) {
                const int jj = h * 8 + j;
                float r;
                r = __builtin_amdgcn_fractf(fmaf(xv[j].x, iw0x, bp0x));
                aC0[jj] += __builtin_amdgcn_cosf(r);
                aS0[jj] += __builtin_amdgcn_sinf(r);
                r = __builtin_amdgcn_fractf(fmaf(xv[j].y, iw0y, bp0y));
                aC0[jj] += __builtin_amdgcn_cosf(r);
                aS0[jj] += __builtin_amdgcn_sinf(r);
                r = __builtin_amdgcn_fractf(fmaf(xv[j].x, iw1x, bp1x));
                aC1[jj] += __builtin_amdgcn_cosf(r);
                aS1[jj] += __builtin_amdgcn_sinf(r);
                r = __builtin_amdgcn_fractf(fmaf(xv[j].y, iw1y, bp1y));
                aC1[jj] += __builtin_amdgcn_cosf(r);
                aS1[jj] += __builtin_amdgcn_sinf(r);
            }
        }
    }

    // ---- epilogue: per-wave reduce of 4 acc sets across 64 lanes ----------
    float* sl = sl_all[w];                 // private per-wave slice, no sync
    const int g  = lane >> 4;
    const int bb = lane & 15;

    float sC0, sS0, sC1, sS1;
    {
        #pragma unroll
        for (int j = 0; j < 16; ++j) sl[j * 64 + (lane ^ j)] = aC0[j];
        float s = 0.f;
        #pragma unroll
        for (int k = 0; k < 16; ++k) s += sl[bb * 64 + ((g * 16 + k) ^ bb)];
        sC0 = s;
        #pragma unroll
        for (int j = 0; j < 16; ++j) sl[j * 64 + (lane ^ j)] = aS0[j];
        s = 0.f;
        #pragma unroll
        for (int k = 0; k < 16; ++k) s += sl[bb * 64 + ((g * 16 + k) ^ bb)];
        sS0 = s;
        #pragma unroll
        for (int j = 0; j < 16; ++j) sl[j * 64 + (lane ^ j)] = aC1[j];
        s = 0.f;
        #pragma unroll
        for (int k = 0; k < 16; ++k) s += sl[bb * 64 + ((g * 16 + k) ^ bb)];
        sC1 = s;
        #pragma unroll
        for (int j = 0; j < 16; ++j) sl[j * 64 + (lane ^ j)] = aS1[j];
        s = 0.f;
        #pragma unroll
        for (int k = 0; k < 16; ++k) s += sl[bb * 64 + ((g * 16 + k) ^ bb)];
        sS1 = s;
    }

    sC0 += __shfl_xor(sC0, 16);  sS0 += __shfl_xor(sS0, 16);
    sC1 += __shfl_xor(sC1, 16);  sS1 += __shfl_xor(sS1, 16);
    sC0 += __shfl_xor(sC0, 32);  sS0 += __shfl_xor(sS0, 32);
    sC1 += __shfl_xor(sC1, 32);  sS1 += __shfl_xor(sS1, 32);

    if (lane < 16) {
        const int b  = bq * 16 + lane;
        const float tv = t[b];
        const float ct = cosf(tv), st = sinf(tv);
        S2[n0 * 64 + b] = make_float2(ct * sC0 - st * sS0,
                                      st * sC0 + ct * sS0);
        S2[n1 * 64 + b] = make_float2(ct * sC1 - st * sS1,
                                      st * sC1 + ct * sS1);
    }
}

// ---------------------------------------------------------------------------
// Kernel 2: split-K GEMM (unchanged).
// out^T[d][b] = sum_n Pr[d][n]*c[n][b] + Pi[d][n]*s[n][b]
// grid = (128 d-tiles of 8, 8 k-chunks of 256).  Wave: 2 d-rows, lanes = b.
// ---------------------------------------------------------------------------
__global__ __launch_bounds__(256) void k_gemm(
    const float2* __restrict__ S2, const float* __restrict__ Pr,
    const float* __restrict__ Pi, float* __restrict__ partial)
{
    const int lane = threadIdx.x & 63;
    const int wid  = __builtin_amdgcn_readfirstlane(threadIdx.x >> 6);
    const int d0   = blockIdx.x * 8 + wid * 2;
    const int k0   = blockIdx.y * 256;

    const float* pr = Pr + (size_t)d0 * 2048 + k0;
    const float* pi = Pi + (size_t)d0 * 2048 + k0;

    float a0 = 0.f, a1 = 0.f;

    for (int kk = 0; kk < 256; kk += 8) {
        float2 cs[8];
        #pragma unroll
        for (int i = 0; i < 8; ++i)
            cs[i] = S2[(size_t)(k0 + kk + i) * 64 + lane];
        #pragma unroll
        for (int i = 0; i < 8; ++i) {
            a0 += pr[kk + i]        * cs[i].x + pi[kk + i]        * cs[i].y;
            a1 += pr[2048 + kk + i] * cs[i].x + pi[2048 + kk + i] * cs[i].y;
        }
    }

    float* p = partial + ((size_t)blockIdx.y * 1024 + d0) * 64 + lane;
    p[0]  = a0;
    p[64] = a1;
}

// ---------------------------------------------------------------------------
// Kernel 3: reduce 8 split-K partials + SiLU (unchanged).
// ---------------------------------------------------------------------------
__global__ __launch_bounds__(256, 4) void k_reduce_silu(
    const float* __restrict__ partial, float* __restrict__ out)
{
    const int lane = threadIdx.x & 63;
    const int gw   = blockIdx.x * 4 + (threadIdx.x >> 6);
    const int b    = gw >> 4;
    const int d    = ((gw & 15) << 6) + lane;

    float s = 0.f;
    #pragma unroll
    for (int ss = 0; ss < 8; ++ss)
        s += partial[((size_t)ss * 1024 + d) * 64 + b];

    float sig = 1.0f / (1.0f + __expf(-s));
    out[(size_t)b * 1024 + d] = s * sig;
}

// ---------------------------------------------------------------------------
extern "C" void kernel_launch(void* const* d_in, const int* in_sizes, int n_in,
                              void* d_out, int out_size, void* d_ws, size_t ws_size,
                              hipStream_t stream)
{
    const float* x  = (const float*)d_in[0];   // (64,1024)
    const float* t  = (const float*)d_in[1];   // (64,)
    const float* W  = (const float*)d_in[2];   // (2048,1024)
    const float* Bp = (const float*)d_in[3];   // (2048,1024)
    const float* Pr = (const float*)d_in[4];   // (1024,2048)
    const float* Pi = (const float*)d_in[5];   // (1024,2048)
    // d_in[6], d_in[7]: sin/cos LUT — superseded by hw sin/cos

    float*  out     = (float*)d_out;                       // (64,1024) f32
    float2* S2      = (float2*)d_ws;                       // 1 MB
    float*  partial = (float*)((char*)d_ws + (1 << 20));   // 2 MB

    k_sums<<<1024, 256, 0, stream>>>(x, t, W, Bp, S2);
    k_gemm<<<dim3(128, 8), 256, 0, stream>>>(S2, Pr, Pi, partial);
    k_reduce_silu<<<256, 256, 0, stream>>>(partial, out);
}